// Round 1
// baseline (2091.544 us; speedup 1.0000x reference)
//
#include <hip/hip_runtime.h>
#include <math.h>

#define T_LEN 24
#define NUU 2000
#define NLL 5000
#define NE 40000
#define CH 128
#define NH 4
#define HD 32
#define TCHUNK 8

static inline int cdiv(int a, int b) { return (a + b - 1) / b; }

// ---------------- CSR build ----------------
__global__ void fill_zero_int(int* __restrict__ p, int n) {
    int i = blockIdx.x * blockDim.x + threadIdx.x;
    if (i < n) p[i] = 0;
}

__global__ void histo_kernel(const int* __restrict__ dst, int* __restrict__ deg, int n) {
    int idx = blockIdx.x * blockDim.x + threadIdx.x;
    if (idx >= T_LEN * NE) return;
    int t = idx / NE;
    atomicAdd(&deg[t * n + dst[idx]], 1);
}

__global__ __launch_bounds__(256) void scan_off(const int* __restrict__ deg, int* __restrict__ offo, int n) {
    __shared__ int part[256];
    int t = blockIdx.x, tid = threadIdx.x;
    int items = (n + 255) / 256;
    int start = tid * items, end = min(start + items, n);
    const int* dt = deg + t * n;
    int s = 0;
    for (int i = start; i < end; ++i) s += dt[i];
    part[tid] = s;
    __syncthreads();
    for (int d = 1; d < 256; d <<= 1) {
        int v = (tid >= d) ? part[tid - d] : 0;
        __syncthreads();
        part[tid] += v;
        __syncthreads();
    }
    int run = part[tid] - s;  // exclusive prefix
    int* ot = offo + t * (n + 1);
    if (tid == 0) ot[0] = 0;
    for (int i = start; i < end; ++i) { run += dt[i]; ot[i + 1] = run; }
}

__global__ void copy_cur(const int* __restrict__ offo, int* __restrict__ cur, int n) {
    int idx = blockIdx.x * blockDim.x + threadIdx.x;
    if (idx >= T_LEN * n) return;
    int t = idx / n, i = idx - t * n;
    cur[idx] = offo[t * (n + 1) + i];
}

__global__ void scatter_perm(const int* __restrict__ dst, int* __restrict__ cur,
                             int* __restrict__ perm, int n) {
    int idx = blockIdx.x * blockDim.x + threadIdx.x;
    if (idx >= T_LEN * NE) return;
    int t = idx / NE, e = idx - t * NE;
    int d = dst[idx];
    int pos = atomicAdd(&cur[t * n + d], 1);
    perm[t * NE + pos] = e;
}

// ---------------- fused relation weights ----------------
// Wf[c, 0:128]   = Wq ;                 bf[0:128]   = bq
// Wf[c, 128+h*32+e] = sum_d Wk[c,h*32+d]*ra[h,d,e];  bias likewise
// Wf[c, 256+h*32+e] = sum_d Wv[c,h*32+d]*rm[h,d,e]
__global__ __launch_bounds__(256) void build_fused(
    const float* __restrict__ w,   // [4,128,128] (layer base)
    const float* __restrict__ b,   // [4,128]
    const float* __restrict__ ra,  // [H,32,32]
    const float* __restrict__ rm,  // [H,32,32]
    float* __restrict__ Wf, float* __restrict__ bf) {
    int idx = blockIdx.x * 256 + threadIdx.x;
    if (idx >= 128 * 384) return;
    int c = idx / 384, col = idx - c * 384;
    if (col < 128) {
        Wf[c * 384 + col] = w[16384 + c * 128 + col];
        if (c == 0) bf[col] = b[128 + col];
    } else {
        int sec = (col - 128) >> 7;
        int hc = (col - 128) & 127;
        int h = hc >> 5, e2 = hc & 31;
        const float* A = (sec == 0 ? ra : rm) + h * 1024;
        const float* wsrc = w + (sec == 0 ? 0 : 2) * 16384;
        const float* bsrc = b + (sec == 0 ? 0 : 2) * 128;
        float s = 0.f, sb = 0.f;
#pragma unroll
        for (int d = 0; d < 32; ++d) {
            float a = A[d * 32 + e2];
            s += wsrc[c * 128 + h * 32 + d] * a;
            sb += bsrc[h * 32 + d] * a;
        }
        Wf[c * 384 + col] = s;
        if (c == 0) bf[col] = sb;
    }
}

// ---------------- GEMM: C[M,NC] = epi( A[M,128] @ W[128,NC] + bias ) ----------------
// GATHER: A row index via ids. EPI: 0 none, 1 relu, 2 skip-blend (g*v + (1-g)*Xold)
template <bool GATHER, int EPI>
__global__ __launch_bounds__(256) void gemm_k128(
    const float* __restrict__ A, const int* __restrict__ ids,
    const float* __restrict__ W, const float* __restrict__ bias,
    float* __restrict__ C, const float* __restrict__ Xold,
    const float* __restrict__ skipPtr, int M, int NC) {
    __shared__ float As[32][68];
    __shared__ float Bs[32][68];
    const int tid = threadIdx.x;
    const int tx = tid & 15, ty = tid >> 4;
    const int m0 = blockIdx.x * 64, n0 = blockIdx.y * 64;

    const int lam = tid >> 2;        // 0..63 tile row
    const int lak = (tid & 3) * 8;   // k offset in chunk
    const int lbk = tid >> 3;        // 0..31
    const int lbn = (tid & 7) * 8;

    int arow = m0 + lam;
    if (GATHER) arow = ids[arow];
    const float* aptr = A + (size_t)arow * 128 + lak;
    const float* bptr = W + (size_t)lbk * NC + n0 + lbn;

    float acc[4][4];
#pragma unroll
    for (int i = 0; i < 4; i++)
#pragma unroll
        for (int j = 0; j < 4; j++) acc[i][j] = 0.f;

#pragma unroll
    for (int kt = 0; kt < 4; ++kt) {
        float4 av0 = *(const float4*)(aptr + kt * 32);
        float4 av1 = *(const float4*)(aptr + kt * 32 + 4);
        float4 bv0 = *(const float4*)(bptr + (size_t)(kt * 32) * NC);
        float4 bv1 = *(const float4*)(bptr + (size_t)(kt * 32) * NC + 4);
        __syncthreads();
        As[lak + 0][lam] = av0.x; As[lak + 1][lam] = av0.y;
        As[lak + 2][lam] = av0.z; As[lak + 3][lam] = av0.w;
        As[lak + 4][lam] = av1.x; As[lak + 5][lam] = av1.y;
        As[lak + 6][lam] = av1.z; As[lak + 7][lam] = av1.w;
        *(float4*)&Bs[lbk][lbn] = bv0;
        *(float4*)&Bs[lbk][lbn + 4] = bv1;
        __syncthreads();
#pragma unroll
        for (int kk = 0; kk < 32; ++kk) {
            float a4[4], b4[4];
            *(float4*)a4 = *(const float4*)&As[kk][ty * 4];
            *(float4*)b4 = *(const float4*)&Bs[kk][tx * 4];
#pragma unroll
            for (int i = 0; i < 4; i++)
#pragma unroll
                for (int j = 0; j < 4; j++) acc[i][j] = fmaf(a4[i], b4[j], acc[i][j]);
        }
    }

    float g = 0.f;
    if (EPI == 2) g = 1.f / (1.f + expf(-skipPtr[0]));
#pragma unroll
    for (int i = 0; i < 4; i++) {
        int r = m0 + ty * 4 + i;
        float vv[4];
#pragma unroll
        for (int j = 0; j < 4; j++) {
            int c = n0 + tx * 4 + j;
            float x = acc[i][j] + bias[c];
            if (EPI == 1) x = fmaxf(x, 0.f);
            vv[j] = x;
        }
        if (EPI == 2) {
            float xo4[4];
            *(float4*)xo4 = *(const float4*)(Xold + (size_t)r * NC + n0 + tx * 4);
#pragma unroll
            for (int j = 0; j < 4; j++) vv[j] = g * vv[j] + (1.f - g) * xo4[j];
        }
        *(float4*)(C + (size_t)r * NC + n0 + tx * 4) = *(float4*)vv;
    }
}

// ---------------- edge aggregation (online segment softmax, folded) ----------------
// one thread per (t_local, dst_node, head)
__global__ __launch_bounds__(256) void agg_edges(
    const float* __restrict__ qkmD,  // [TCHUNK*nDst, 384] q at cols 0..127
    const float* __restrict__ qkmS,  // [TCHUNK*nSrc, 384] kr at 128.., mr at 256..
    const int* __restrict__ off,     // [T_LEN, nDst+1]
    const int* __restrict__ perm,    // [T_LEN, NE]
    const int* __restrict__ srcA,    // [T_LEN, NE]
    const float* __restrict__ relp,  // [H]
    float* __restrict__ agg,         // [TCHUNK*nDst, 128]
    int nDst, int nSrc, int tBase) {
    int idx = blockIdx.x * 256 + threadIdx.x;
    int total = TCHUNK * nDst * NH;
    if (idx >= total) return;
    int h = idx & 3;
    int node = (idx >> 2) % nDst;
    int tl = (idx >> 2) / nDst;
    int t = tBase + tl;

    size_t drow = (size_t)(tl * nDst + node);
    const float* qp = qkmD + drow * 384 + h * HD;
    float qr[HD];
#pragma unroll
    for (int d = 0; d < HD; d++) qr[d] = qp[d];
    float p = relp[h] * 0.17677669529663687f;  // 1/sqrt(32)

    float m = -INFINITY, z = 0.f;
    float acc[HD];
#pragma unroll
    for (int d = 0; d < HD; d++) acc[d] = 0.f;

    int e0 = off[t * (nDst + 1) + node], e1 = off[t * (nDst + 1) + node + 1];
    const int* permT = perm + (size_t)t * NE;
    const int* srcT = srcA + (size_t)t * NE;
    for (int i = e0; i < e1; ++i) {
        int e = permT[i];
        int s = srcT[e];
        const float* kp = qkmS + ((size_t)(tl * nSrc + s)) * 384 + 128 + h * HD;
        float dot = 0.f;
#pragma unroll
        for (int d = 0; d < HD; d++) dot = fmaf(qr[d], kp[d], dot);
        float l = dot * p;
        if (l > m) {
            float c = expf(m - l);  // m=-inf -> 0
            z *= c;
#pragma unroll
            for (int d = 0; d < HD; d++) acc[d] *= c;
            m = l;
        }
        float w = expf(l - m);
        z += w;
        const float* mp = kp + 128;
#pragma unroll
        for (int d = 0; d < HD; d++) acc[d] = fmaf(w, mp[d], acc[d]);
    }
    float inv = 1.f / (z + 1e-16f);
    float* op = agg + drow * CH + h * HD;
#pragma unroll
    for (int d = 0; d < HD; d++) op[d] = acc[d] * inv;
}

__global__ void gelu_ip(float* __restrict__ x, int n) {
    int idx = blockIdx.x * blockDim.x + threadIdx.x;
    if (idx >= n) return;
    float v = x[idx];
    x[idx] = 0.5f * v * (1.f + erff(v * 0.70710678118654752f));
}

__global__ void gather_traj(const float* __restrict__ tkg, const int* __restrict__ traj,
                            const int* __restrict__ tki, float* __restrict__ outp) {
    int idx = blockIdx.x * blockDim.x + threadIdx.x;
    if (idx >= 64 * 128 * 128) return;
    int r = idx >> 7, c2 = idx & 127;
    int t = tki[r], n = traj[r];
    outp[idx] = tkg[((size_t)t * NLL + n) * CH + c2];
}

// ---------------- launch ----------------
extern "C" void kernel_launch(void* const* d_in, const int* in_sizes, int n_in,
                              void* d_out, int out_size, void* d_ws, size_t ws_size,
                              hipStream_t stream) {
    (void)in_sizes; (void)n_in; (void)out_size; (void)ws_size;
    const float* user_emb = (const float*)d_in[0];
    const float* loc_emb = (const float*)d_in[1];
    const float* lin_user_w = (const float*)d_in[2];
    const float* lin_user_b = (const float*)d_in[3];
    const float* lin_loc_w = (const float*)d_in[4];
    const float* lin_loc_b = (const float*)d_in[5];
    const float* w_user = (const float*)d_in[6];
    const float* b_user = (const float*)d_in[7];
    const float* w_loc = (const float*)d_in[8];
    const float* b_loc = (const float*)d_in[9];
    const float* rel_a = (const float*)d_in[10];
    const float* rel_m = (const float*)d_in[11];
    const float* rel_p = (const float*)d_in[12];
    const float* skip = (const float*)d_in[13];
    const float* lin2_w = (const float*)d_in[14];
    const float* lin2_b = (const float*)d_in[15];
    const int* user_ids = (const int*)d_in[16];
    const int* loc_ids = (const int*)d_in[17];
    const int* ei_ul_src = (const int*)d_in[18];
    const int* ei_ul_dst = (const int*)d_in[19];
    const int* ei_lu_src = (const int*)d_in[20];
    const int* ei_lu_dst = (const int*)d_in[21];
    const int* traj = (const int*)d_in[22];
    const int* tkg_idx = (const int*)d_in[23];
    float* outp = (float*)d_out;

    // workspace carve (~210 MB)
    size_t woff = 0;
    char* base = (char*)d_ws;
    auto carve = [&](size_t bytes) -> void* {
        void* p = base + woff;
        woff += (bytes + 255) & ~(size_t)255;
        return p;
    };
    float* xu = (float*)carve((size_t)T_LEN * NUU * 128 * 4);
    float* xl = (float*)carve((size_t)T_LEN * NLL * 128 * 4);
    float* qkm_u = (float*)carve((size_t)TCHUNK * NUU * 384 * 4);
    float* qkm_l = (float*)carve((size_t)TCHUNK * NLL * 384 * 4);
    float* agg_u = (float*)carve((size_t)TCHUNK * NUU * 128 * 4);
    float* agg_l = (float*)carve((size_t)TCHUNK * NLL * 128 * 4);
    float* wf_u = (float*)carve(128 * 384 * 4);
    float* bf_u = (float*)carve(384 * 4);
    float* wf_l = (float*)carve(128 * 384 * 4);
    float* bf_l = (float*)carve(384 * 4);
    int* deg_ul = (int*)carve((size_t)T_LEN * NLL * 4);
    int* cur_ul = (int*)carve((size_t)T_LEN * NLL * 4);
    int* off_ul = (int*)carve((size_t)T_LEN * (NLL + 1) * 4);
    int* perm_ul = (int*)carve((size_t)T_LEN * NE * 4);
    int* deg_lu = (int*)carve((size_t)T_LEN * NUU * 4);
    int* cur_lu = (int*)carve((size_t)T_LEN * NUU * 4);
    int* off_lu = (int*)carve((size_t)T_LEN * (NUU + 1) * 4);
    int* perm_lu = (int*)carve((size_t)T_LEN * NE * 4);

    // ---- CSR build (dst-sorted edge lists per snapshot) ----
    fill_zero_int<<<cdiv(T_LEN * NLL, 256), 256, 0, stream>>>(deg_ul, T_LEN * NLL);
    fill_zero_int<<<cdiv(T_LEN * NUU, 256), 256, 0, stream>>>(deg_lu, T_LEN * NUU);
    histo_kernel<<<cdiv(T_LEN * NE, 256), 256, 0, stream>>>(ei_ul_dst, deg_ul, NLL);
    histo_kernel<<<cdiv(T_LEN * NE, 256), 256, 0, stream>>>(ei_lu_dst, deg_lu, NUU);
    scan_off<<<T_LEN, 256, 0, stream>>>(deg_ul, off_ul, NLL);
    scan_off<<<T_LEN, 256, 0, stream>>>(deg_lu, off_lu, NUU);
    copy_cur<<<cdiv(T_LEN * NLL, 256), 256, 0, stream>>>(off_ul, cur_ul, NLL);
    copy_cur<<<cdiv(T_LEN * NUU, 256), 256, 0, stream>>>(off_lu, cur_lu, NUU);
    scatter_perm<<<cdiv(T_LEN * NE, 256), 256, 0, stream>>>(ei_ul_dst, cur_ul, perm_ul, NLL);
    scatter_perm<<<cdiv(T_LEN * NE, 256), 256, 0, stream>>>(ei_lu_dst, cur_lu, perm_lu, NUU);

    // ---- embed + linear + relu ----
    gemm_k128<true, 1><<<dim3(T_LEN * NUU / 64, 2), 256, 0, stream>>>(
        user_emb, user_ids, lin_user_w, lin_user_b, xu, nullptr, nullptr, T_LEN * NUU, 128);
    gemm_k128<true, 1><<<dim3(T_LEN * NLL / 64, 2), 256, 0, stream>>>(
        loc_emb, loc_ids, lin_loc_w, lin_loc_b, xl, nullptr, nullptr, T_LEN * NLL, 128);

    // ---- HGT layers ----
    for (int l = 0; l < 2; ++l) {
        build_fused<<<cdiv(128 * 384, 256), 256, 0, stream>>>(
            w_user + (size_t)l * 4 * 16384, b_user + l * 512,
            rel_a + (size_t)(l * 2 + 0) * 4096, rel_m + (size_t)(l * 2 + 0) * 4096, wf_u, bf_u);
        build_fused<<<cdiv(128 * 384, 256), 256, 0, stream>>>(
            w_loc + (size_t)l * 4 * 16384, b_loc + l * 512,
            rel_a + (size_t)(l * 2 + 1) * 4096, rel_m + (size_t)(l * 2 + 1) * 4096, wf_l, bf_l);

        for (int tb = 0; tb < T_LEN; tb += TCHUNK) {
            const int MU = TCHUNK * NUU;   // 16000
            const int ML = TCHUNK * NLL;   // 40000
            float* xu_c = xu + (size_t)tb * NUU * 128;
            float* xl_c = xl + (size_t)tb * NLL * 128;

            gemm_k128<false, 0><<<dim3(MU / 64, 6), 256, 0, stream>>>(
                xu_c, nullptr, wf_u, bf_u, qkm_u, nullptr, nullptr, MU, 384);
            gemm_k128<false, 0><<<dim3(ML / 64, 6), 256, 0, stream>>>(
                xl_c, nullptr, wf_l, bf_l, qkm_l, nullptr, nullptr, ML, 384);

            agg_edges<<<cdiv(TCHUNK * NLL * NH, 256), 256, 0, stream>>>(
                qkm_l, qkm_u, off_ul, perm_ul, ei_ul_src, rel_p + (l * 2 + 0) * 4,
                agg_l, NLL, NUU, tb);
            agg_edges<<<cdiv(TCHUNK * NUU * NH, 256), 256, 0, stream>>>(
                qkm_u, qkm_l, off_lu, perm_lu, ei_lu_src, rel_p + (l * 2 + 1) * 4,
                agg_u, NUU, NLL, tb);

            gelu_ip<<<cdiv(MU * 128, 256), 256, 0, stream>>>(agg_u, MU * 128);
            gelu_ip<<<cdiv(ML * 128, 256), 256, 0, stream>>>(agg_l, ML * 128);

            gemm_k128<false, 2><<<dim3(MU / 64, 2), 256, 0, stream>>>(
                agg_u, nullptr, w_user + (size_t)(l * 4 + 3) * 16384, b_user + l * 512 + 384,
                xu_c, xu_c, skip + l * 2 + 0, MU, 128);
            gemm_k128<false, 2><<<dim3(ML / 64, 2), 256, 0, stream>>>(
                agg_l, nullptr, w_loc + (size_t)(l * 4 + 3) * 16384, b_loc + l * 512 + 384,
                xl_c, xl_c, skip + l * 2 + 1, ML, 128);
        }
    }

    // ---- lin2 -> tkg_out region of d_out ----
    float* tkg_out = outp + (size_t)64 * 128 * 128;
    gemm_k128<false, 0><<<dim3(T_LEN * NLL / 64, 2), 256, 0, stream>>>(
        xl, nullptr, lin2_w, lin2_b, tkg_out, nullptr, nullptr, T_LEN * NLL, 128);

    // ---- trajectory gather -> first region of d_out ----
    gather_traj<<<cdiv(64 * 128 * 128, 256), 256, 0, stream>>>(tkg_out, traj, tkg_idx, outp);
}